// Round 1
// baseline (344.409 us; speedup 1.0000x reference)
//
#include <hip/hip_runtime.h>
#include <hip/hip_bf16.h>
#include <hip/hip_fp16.h>

#define N_NODES 50000
#define N_EDGES 1600000
#define NPB    50      // nodes per bucket
#define NBUK   1000    // NPB*NBUK == N_NODES
#define NSL    8       // XCD slices
#define BCAPS  320     // slots per (bucket,slice): mean 200, +8.5 sigma
#define BCAPH  1280    // 4*BCAPS, per bucket-half

typedef __attribute__((ext_vector_type(8))) short short8;
typedef __attribute__((ext_vector_type(4))) float f32x4;

__device__ __forceinline__ unsigned short f2bf(float f) {
  union { float f; unsigned int i; } v; v.f = f;
  unsigned int i = v.i;
  unsigned int r = i + 0x7FFFu + ((i >> 16) & 1u);
  return (unsigned short)(r >> 16);
}

// ---------------- Kernel 1: x = h @ W  (fp32 in, bf16 MFMA, f32 out) -------
__global__ __launch_bounds__(256) void k_x(const float* __restrict__ hmat,
                                           const float* __restrict__ Wmat,
                                           float* __restrict__ x) {
  __shared__ unsigned short Wt[64 * 264];  // Wt[n][k], row stride 264 (16B-aligned)
  const int t = threadIdx.x;
  for (int idx = t; idx < 64 * 256; idx += 256) {
    int k = idx >> 6, n = idx & 63;        // global read coalesced (idx = k*64+n)
    Wt[n * 264 + k] = f2bf(Wmat[idx]);
  }
  __syncthreads();
  const int wave = t >> 6, lane = t & 63;
  const int quad = lane >> 4, l16 = lane & 15;
  const int m0 = blockIdx.x * 64 + wave * 16;
  int arow = m0 + l16; if (arow >= N_NODES) arow = N_NODES - 1;  // clamp: rows independent
  f32x4 c[4] = {{0,0,0,0},{0,0,0,0},{0,0,0,0},{0,0,0,0}};
  const float* aptr = hmat + (size_t)arow * 256 + quad * 8;
  #pragma unroll
  for (int kb = 0; kb < 8; ++kb) {
    f32x4 a0 = *(const f32x4*)(aptr + kb * 32);
    f32x4 a1 = *(const f32x4*)(aptr + kb * 32 + 4);
    short8 a;
    a[0] = (short)f2bf(a0[0]); a[1] = (short)f2bf(a0[1]);
    a[2] = (short)f2bf(a0[2]); a[3] = (short)f2bf(a0[3]);
    a[4] = (short)f2bf(a1[0]); a[5] = (short)f2bf(a1[1]);
    a[6] = (short)f2bf(a1[2]); a[7] = (short)f2bf(a1[3]);
    #pragma unroll
    for (int nt = 0; nt < 4; ++nt) {
      int n = nt * 16 + l16;
      short8 b = *(const short8*)(&Wt[n * 264 + kb * 32 + quad * 8]);
      c[nt] = __builtin_amdgcn_mfma_f32_16x16x32_bf16(a, b, c[nt], 0, 0, 0);
    }
  }
  #pragma unroll
  for (int nt = 0; nt < 4; ++nt) {
    #pragma unroll
    for (int r = 0; r < 4; ++r) {
      int grow = m0 + quad * 4 + r;
      if (grow < N_NODES) x[grow * 64 + nt * 16 + l16] = c[nt][r];
    }
  }
}

// ---------------- Kernel 2: el = x@Wl^T, er = x@Wr^T (wave per row) ---------
__global__ __launch_bounds__(256) void k_eler(const float* __restrict__ x,
    const float* __restrict__ Wl, const float* __restrict__ Wr,
    float* __restrict__ el, float* __restrict__ er) {
  const int lane = threadIdx.x & 63;
  const int gw = (blockIdx.x * 256 + threadIdx.x) >> 6;
  const int nw = gridDim.x * 4;
  float wl[4], wr[4];
  #pragma unroll
  for (int hh = 0; hh < 4; ++hh) {
    wl[hh] = Wl[hh * 64 + lane];
    wr[hh] = Wr[hh * 64 + lane];
  }
  for (int r = gw; r < N_NODES; r += nw) {
    float xv = x[r * 64 + lane];
    float p[4], q[4];
    #pragma unroll
    for (int hh = 0; hh < 4; ++hh) { p[hh] = xv * wl[hh]; q[hh] = xv * wr[hh]; }
    #pragma unroll
    for (int off = 32; off > 0; off >>= 1) {
      #pragma unroll
      for (int hh = 0; hh < 4; ++hh) {
        p[hh] += __shfl_xor(p[hh], off, 64);
        q[hh] += __shfl_xor(q[hh], off, 64);
      }
    }
    if (lane == 0) {
      f32x4 pv = {p[0], p[1], p[2], p[3]};
      f32x4 qv = {q[0], q[1], q[2], q[3]};
      ((f32x4*)el)[r] = pv;
      ((f32x4*)er)[r] = qv;
    }
  }
}

// ---------------- Kernel 3: XCD-sliced bucket partition ---------------------
// slice = blockIdx&7 ~ XCD id (round-robin dispatch heuristic). Each
// (bucket,slice) sub-list is filled by one XCD only -> lines written once,
// cursor atomics XCD-local with 8x less contention.
__global__ __launch_bounds__(256) void k_part(const int* __restrict__ ei,
                                              int* __restrict__ bcnt,
                                              unsigned int* __restrict__ raw) {
  int e = blockIdx.x * 256 + threadIdx.x;
  int slice = blockIdx.x & 7;
  if (e < N_EDGES) {
    int s = ei[e], d = ei[N_EDGES + e];
    int b  = s / NPB;
    int sl = s - b * NPB;
    int cell = b * NSL + slice;
    int pos = atomicAdd(&bcnt[cell * 16], 1);
    if (pos < BCAPS)
      raw[(size_t)cell * BCAPS + pos] = ((unsigned int)d << 8) | (unsigned int)sl;
  }
}

// ---------------- Kernel 4: per-bucket-half CSR + edge weights --------------
// Grid 2000: b = blk>>1, half = blk&1 handles slices 4*half..4*half+3.
__global__ __launch_bounds__(256) void k_bucket(const unsigned int* __restrict__ raw,
    const int* __restrict__ bcnt,
    const float* __restrict__ el, const float* __restrict__ er,
    int4* __restrict__ recs, int* __restrict__ rs_s, int* __restrict__ rs_e) {
  __shared__ unsigned int sraw[BCAPH];
  __shared__ int pref[NPB + 1];
  __shared__ int cur[NPB];
  const int b = blockIdx.x >> 1, H = blockIdx.x & 1, t = threadIdx.x;
  const int s0 = H * 4;
  int c0 = bcnt[(b * NSL + s0 + 0) * 16]; if (c0 > BCAPS) c0 = BCAPS;
  int c1 = bcnt[(b * NSL + s0 + 1) * 16]; if (c1 > BCAPS) c1 = BCAPS;
  int c2 = bcnt[(b * NSL + s0 + 2) * 16]; if (c2 > BCAPS) c2 = BCAPS;
  int c3 = bcnt[(b * NSL + s0 + 3) * 16]; if (c3 > BCAPS) c3 = BCAPS;
  const int o1 = c0, o2 = c0 + c1, o3 = c0 + c1 + c2, cnt = o3 + c3;
  if (t <= NPB) pref[t] = 0;
  __syncthreads();
  for (int j = t; j < c0; j += 256) { unsigned int r = raw[(size_t)(b*NSL+s0+0)*BCAPS + j]; sraw[j]      = r; atomicAdd(&pref[(int)(r & 255u) + 1], 1); }
  for (int j = t; j < c1; j += 256) { unsigned int r = raw[(size_t)(b*NSL+s0+1)*BCAPS + j]; sraw[o1 + j] = r; atomicAdd(&pref[(int)(r & 255u) + 1], 1); }
  for (int j = t; j < c2; j += 256) { unsigned int r = raw[(size_t)(b*NSL+s0+2)*BCAPS + j]; sraw[o2 + j] = r; atomicAdd(&pref[(int)(r & 255u) + 1], 1); }
  for (int j = t; j < c3; j += 256) { unsigned int r = raw[(size_t)(b*NSL+s0+3)*BCAPS + j]; sraw[o3 + j] = r; atomicAdd(&pref[(int)(r & 255u) + 1], 1); }
  __syncthreads();
  if (t == 0) {
    int run = 0;
    #pragma unroll
    for (int n = 0; n <= NPB; ++n) { run += pref[n]; pref[n] = run; }
  }
  __syncthreads();
  const int wbase = (b * 2 + H) * BCAPH;   // this half's window in recs
  if (t < NPB) {
    cur[t] = pref[t];
    rs_s[H * N_NODES + b * NPB + t] = wbase + pref[t];
    rs_e[H * N_NODES + b * NPB + t] = wbase + pref[t + 1];
  }
  __syncthreads();
  const int base = b * NPB;
  for (int j = t; j < cnt; j += 256) {
    unsigned int r = sraw[j];
    int sl = (int)(r & 255u);
    int d  = (int)(r >> 8);
    int pos = atomicAdd(&cur[sl], 1);
    f32x4 a = ((const f32x4*)el)[base + sl];   // L1-resident (800B/bucket)
    f32x4 e = ((const f32x4*)er)[d];           // L2-resident (800 KB)
    float w[4];
    #pragma unroll
    for (int hh = 0; hh < 4; ++hh) {
      float tt = a[hh] + e[hh];
      tt = (tt >= 0.f) ? tt : 0.2f * tt;
      w[hh] = __expf(tt);
    }
    union { __half2 h; int i; } u01, u23;
    u01.h = __floats2half2_rn(w[0], w[1]);
    u23.h = __floats2half2_rn(w[2], w[3]);
    int4 rc; rc.x = d; rc.y = u01.i; rc.z = u23.i; rc.w = 0;
    recs[(size_t)wbase + pos] = rc;            // scattered within 20KB window
  }
}

// ---------------- Kernel 5: fused normalize + SpMM + ELU --------------------
// One wave per node. Edge records are loaded COALESCED (one int4 per lane,
// covers a chunk of 64 edges) and broadcast lane->wave via __shfl, so the
// per-edge critical path is shfl->gather instead of the old
// uniform-load(HBM ~900cy)->gather chain. Gather addresses for a whole chunk
// become available after ONE coalesced load; unrolled gathers then pipeline.
__global__ __launch_bounds__(256) void k_agg(const float* __restrict__ x,
    const int* __restrict__ rs_s, const int* __restrict__ rs_e,
    const int4* __restrict__ recs,
    const float* __restrict__ bvec, float* __restrict__ out) {
  const int node = (blockIdx.x * 256 + threadIdx.x) >> 6;
  const int lane = threadIdx.x & 63;
  if (node >= N_NODES) return;
  float n0 = 0.f, n1 = 0.f, n2 = 0.f, n3 = 0.f;
  float d0 = 0.f, d1 = 0.f, d2 = 0.f, d3 = 0.f;
  #pragma unroll
  for (int hf = 0; hf < 2; ++hf) {
    const int j0 = rs_s[hf * N_NODES + node], j1 = rs_e[hf * N_NODES + node];
    for (int jb = j0; jb < j1; jb += 64) {
      const int rem = j1 - jb;
      const int m = rem < 64 ? rem : 64;
      const int4 r = recs[jb + (lane < m ? lane : 0)];  // coalesced chunk load
      #pragma unroll 4
      for (int e = 0; e < m; ++e) {
        const int dd  = __shfl(r.x, e, 64);
        const int w01 = __shfl(r.y, e, 64);
        const int w23 = __shfl(r.z, e, 64);
        union { int i; __half2 h; } u01, u23;
        u01.i = w01; u23.i = w23;
        const float2 f01 = __half22float2(u01.h);
        const float2 f23 = __half22float2(u23.h);
        const float xv = x[(size_t)dd * 64 + lane];  // coalesced 256B gather
        d0 += f01.x; d1 += f01.y; d2 += f23.x; d3 += f23.y;
        n0 = fmaf(f01.x, xv, n0); n1 = fmaf(f01.y, xv, n1);
        n2 = fmaf(f23.x, xv, n2); n3 = fmaf(f23.y, xv, n3);
      }
    }
  }
  float bv = bvec[lane];
  size_t ob = (size_t)node * 256 + lane;
  float o;
  o = n0 / fmaxf(d0, 1e-12f) + bv; o = (o > 0.f) ? o : (__expf(o) - 1.f); out[ob      ] = o;
  o = n1 / fmaxf(d1, 1e-12f) + bv; o = (o > 0.f) ? o : (__expf(o) - 1.f); out[ob +  64] = o;
  o = n2 / fmaxf(d2, 1e-12f) + bv; o = (o > 0.f) ? o : (__expf(o) - 1.f); out[ob + 128] = o;
  o = n3 / fmaxf(d3, 1e-12f) + bv; o = (o > 0.f) ? o : (__expf(o) - 1.f); out[ob + 192] = o;
}

// ---------------- Launch ----------------------------------------------------
extern "C" void kernel_launch(void* const* d_in, const int* in_sizes, int n_in,
                              void* d_out, int out_size, void* d_ws, size_t ws_size,
                              hipStream_t stream) {
  const float* h  = (const float*)d_in[0];
  const float* W  = (const float*)d_in[1];
  const float* Wl = (const float*)d_in[2];
  const float* Wr = (const float*)d_in[3];
  const float* b  = (const float*)d_in[4];
  const int*   ei = (const int*)d_in[5];
  float* out = (float*)d_out;   // reference output dtype is float32

  char* ws = (char*)d_ws;
  float*        x    = (float*)       (ws + 0);          // 12,800,000
  float*        el   = (float*)       (ws + 12800000);   //    800,000
  float*        er   = (float*)       (ws + 13600000);   //    800,000
  int*          bcnt = (int*)         (ws + 14400000);   // 8000*64  =    512,000
  unsigned int* raw  = (unsigned int*)(ws + 14912000);   // 8000*320*4 = 10,240,000
  int4*         recs = (int4*)        (ws + 25152000);   // 2000*1280*16 = 40,960,000
  int*          rs_s = (int*)         (ws + 66112000);   //    400,000
  int*          rs_e = (int*)         (ws + 66512000);   //    400,000  (end ~66.9 MB)
  (void)ws_size; (void)in_sizes; (void)n_in; (void)out_size;

  hipMemsetAsync(bcnt, 0, 512000, stream);

  k_x      <<<782,   256, 0, stream>>>(h, W, x);
  k_eler   <<<782,   256, 0, stream>>>(x, Wl, Wr, el, er);
  k_part   <<<6250,  256, 0, stream>>>(ei, bcnt, raw);
  k_bucket <<<2000,  256, 0, stream>>>(raw, bcnt, el, er, recs, rs_s, rs_e);
  k_agg    <<<12500, 256, 0, stream>>>(x, rs_s, rs_e, recs, b, out);
}

// Round 2
// 340.098 us; speedup vs baseline: 1.0127x; 1.0127x over previous
//
#include <hip/hip_runtime.h>
#include <hip/hip_bf16.h>
#include <hip/hip_fp16.h>

#define N_NODES 50000
#define N_EDGES 1600000
#define NPB    50      // nodes per bucket
#define NBUK   1000    // NPB*NBUK == N_NODES
#define NSL    8       // XCD slices
#define BCAPS  320     // slots per (bucket,slice): mean 200, +8.5 sigma
#define BCAPH  1280    // 4*BCAPS, per bucket-half

typedef __attribute__((ext_vector_type(8))) short short8;
typedef __attribute__((ext_vector_type(4))) float f32x4;

__device__ __forceinline__ unsigned short f2bf(float f) {
  union { float f; unsigned int i; } v; v.f = f;
  unsigned int i = v.i;
  unsigned int r = i + 0x7FFFu + ((i >> 16) & 1u);
  return (unsigned short)(r >> 16);
}

// ---------------- Kernel 1: x = h @ W  (fp32 in, bf16 MFMA, f32 out) -------
__global__ __launch_bounds__(256) void k_x(const float* __restrict__ hmat,
                                           const float* __restrict__ Wmat,
                                           float* __restrict__ x) {
  __shared__ unsigned short Wt[64 * 264];  // Wt[n][k], row stride 264 (16B-aligned)
  const int t = threadIdx.x;
  for (int idx = t; idx < 64 * 256; idx += 256) {
    int k = idx >> 6, n = idx & 63;        // global read coalesced (idx = k*64+n)
    Wt[n * 264 + k] = f2bf(Wmat[idx]);
  }
  __syncthreads();
  const int wave = t >> 6, lane = t & 63;
  const int quad = lane >> 4, l16 = lane & 15;
  const int m0 = blockIdx.x * 64 + wave * 16;
  int arow = m0 + l16; if (arow >= N_NODES) arow = N_NODES - 1;  // clamp: rows independent
  f32x4 c[4] = {{0,0,0,0},{0,0,0,0},{0,0,0,0},{0,0,0,0}};
  const float* aptr = hmat + (size_t)arow * 256 + quad * 8;
  #pragma unroll
  for (int kb = 0; kb < 8; ++kb) {
    f32x4 a0 = *(const f32x4*)(aptr + kb * 32);
    f32x4 a1 = *(const f32x4*)(aptr + kb * 32 + 4);
    short8 a;
    a[0] = (short)f2bf(a0[0]); a[1] = (short)f2bf(a0[1]);
    a[2] = (short)f2bf(a0[2]); a[3] = (short)f2bf(a0[3]);
    a[4] = (short)f2bf(a1[0]); a[5] = (short)f2bf(a1[1]);
    a[6] = (short)f2bf(a1[2]); a[7] = (short)f2bf(a1[3]);
    #pragma unroll
    for (int nt = 0; nt < 4; ++nt) {
      int n = nt * 16 + l16;
      short8 b = *(const short8*)(&Wt[n * 264 + kb * 32 + quad * 8]);
      c[nt] = __builtin_amdgcn_mfma_f32_16x16x32_bf16(a, b, c[nt], 0, 0, 0);
    }
  }
  #pragma unroll
  for (int nt = 0; nt < 4; ++nt) {
    #pragma unroll
    for (int r = 0; r < 4; ++r) {
      int grow = m0 + quad * 4 + r;
      if (grow < N_NODES) x[grow * 64 + nt * 16 + l16] = c[nt][r];
    }
  }
}

// ---------------- Kernel 2: el = x@Wl^T, er = x@Wr^T (wave per row) ---------
__global__ __launch_bounds__(256) void k_eler(const float* __restrict__ x,
    const float* __restrict__ Wl, const float* __restrict__ Wr,
    float* __restrict__ el, float* __restrict__ er) {
  const int lane = threadIdx.x & 63;
  const int gw = (blockIdx.x * 256 + threadIdx.x) >> 6;
  const int nw = gridDim.x * 4;
  float wl[4], wr[4];
  #pragma unroll
  for (int hh = 0; hh < 4; ++hh) {
    wl[hh] = Wl[hh * 64 + lane];
    wr[hh] = Wr[hh * 64 + lane];
  }
  for (int r = gw; r < N_NODES; r += nw) {
    float xv = x[r * 64 + lane];
    float p[4], q[4];
    #pragma unroll
    for (int hh = 0; hh < 4; ++hh) { p[hh] = xv * wl[hh]; q[hh] = xv * wr[hh]; }
    #pragma unroll
    for (int off = 32; off > 0; off >>= 1) {
      #pragma unroll
      for (int hh = 0; hh < 4; ++hh) {
        p[hh] += __shfl_xor(p[hh], off, 64);
        q[hh] += __shfl_xor(q[hh], off, 64);
      }
    }
    if (lane == 0) {
      f32x4 pv = {p[0], p[1], p[2], p[3]};
      f32x4 qv = {q[0], q[1], q[2], q[3]};
      ((f32x4*)el)[r] = pv;
      ((f32x4*)er)[r] = qv;
    }
  }
}

// ---------------- Kernel 3: XCD-sliced bucket partition ---------------------
// slice = blockIdx&7 ~ XCD id (round-robin dispatch heuristic). Each
// (bucket,slice) sub-list is filled by one XCD only -> lines written once,
// cursor atomics XCD-local with 8x less contention.
__global__ __launch_bounds__(256) void k_part(const int* __restrict__ ei,
                                              int* __restrict__ bcnt,
                                              unsigned int* __restrict__ raw) {
  int e = blockIdx.x * 256 + threadIdx.x;
  int slice = blockIdx.x & 7;
  if (e < N_EDGES) {
    int s = ei[e], d = ei[N_EDGES + e];
    int b  = s / NPB;
    int sl = s - b * NPB;
    int cell = b * NSL + slice;
    int pos = atomicAdd(&bcnt[cell * 16], 1);
    if (pos < BCAPS)
      raw[(size_t)cell * BCAPS + pos] = ((unsigned int)d << 8) | (unsigned int)sl;
  }
}

// ---------------- Kernel 4: per-bucket-half CSR + edge weights --------------
// Grid 2000: b = blk>>1, half = blk&1 handles slices 4*half..4*half+3.
__global__ __launch_bounds__(256) void k_bucket(const unsigned int* __restrict__ raw,
    const int* __restrict__ bcnt,
    const float* __restrict__ el, const float* __restrict__ er,
    int4* __restrict__ recs, int* __restrict__ rs_s, int* __restrict__ rs_e) {
  __shared__ unsigned int sraw[BCAPH];
  __shared__ int pref[NPB + 1];
  __shared__ int cur[NPB];
  const int b = blockIdx.x >> 1, H = blockIdx.x & 1, t = threadIdx.x;
  const int s0 = H * 4;
  int c0 = bcnt[(b * NSL + s0 + 0) * 16]; if (c0 > BCAPS) c0 = BCAPS;
  int c1 = bcnt[(b * NSL + s0 + 1) * 16]; if (c1 > BCAPS) c1 = BCAPS;
  int c2 = bcnt[(b * NSL + s0 + 2) * 16]; if (c2 > BCAPS) c2 = BCAPS;
  int c3 = bcnt[(b * NSL + s0 + 3) * 16]; if (c3 > BCAPS) c3 = BCAPS;
  const int o1 = c0, o2 = c0 + c1, o3 = c0 + c1 + c2, cnt = o3 + c3;
  if (t <= NPB) pref[t] = 0;
  __syncthreads();
  for (int j = t; j < c0; j += 256) { unsigned int r = raw[(size_t)(b*NSL+s0+0)*BCAPS + j]; sraw[j]      = r; atomicAdd(&pref[(int)(r & 255u) + 1], 1); }
  for (int j = t; j < c1; j += 256) { unsigned int r = raw[(size_t)(b*NSL+s0+1)*BCAPS + j]; sraw[o1 + j] = r; atomicAdd(&pref[(int)(r & 255u) + 1], 1); }
  for (int j = t; j < c2; j += 256) { unsigned int r = raw[(size_t)(b*NSL+s0+2)*BCAPS + j]; sraw[o2 + j] = r; atomicAdd(&pref[(int)(r & 255u) + 1], 1); }
  for (int j = t; j < c3; j += 256) { unsigned int r = raw[(size_t)(b*NSL+s0+3)*BCAPS + j]; sraw[o3 + j] = r; atomicAdd(&pref[(int)(r & 255u) + 1], 1); }
  __syncthreads();
  if (t == 0) {
    int run = 0;
    #pragma unroll
    for (int n = 0; n <= NPB; ++n) { run += pref[n]; pref[n] = run; }
  }
  __syncthreads();
  const int wbase = (b * 2 + H) * BCAPH;   // this half's window in recs
  if (t < NPB) {
    cur[t] = pref[t];
    rs_s[H * N_NODES + b * NPB + t] = wbase + pref[t];
    rs_e[H * N_NODES + b * NPB + t] = wbase + pref[t + 1];
  }
  __syncthreads();
  const int base = b * NPB;
  for (int j = t; j < cnt; j += 256) {
    unsigned int r = sraw[j];
    int sl = (int)(r & 255u);
    int d  = (int)(r >> 8);
    int pos = atomicAdd(&cur[sl], 1);
    f32x4 a = ((const f32x4*)el)[base + sl];   // L1-resident (800B/bucket)
    f32x4 e = ((const f32x4*)er)[d];           // L2-resident (800 KB)
    float w[4];
    #pragma unroll
    for (int hh = 0; hh < 4; ++hh) {
      float tt = a[hh] + e[hh];
      tt = (tt >= 0.f) ? tt : 0.2f * tt;
      w[hh] = __expf(tt);
    }
    union { __half2 h; int i; } u01, u23;
    u01.h = __floats2half2_rn(w[0], w[1]);
    u23.h = __floats2half2_rn(w[2], w[3]);
    int4 rc; rc.x = d; rc.y = u01.i; rc.z = u23.i; rc.w = 0;
    recs[(size_t)wbase + pos] = rc;            // scattered within 20KB window
  }
}

// ---------------- Kernel 5: fused normalize + SpMM + ELU --------------------
// One wave per node; per-node edges live in two half-ranges.
// Wave-uniform rec loads + DEEP unroll (8): the compiler hoists 8 independent
// rec loads, then issues the 8 dependent x-gathers — 8 two-level chains in
// flight (round -1 structure was 4-deep at 82us; shfl variant regressed).
__global__ __launch_bounds__(256) void k_agg(const float* __restrict__ x,
    const int* __restrict__ rs_s, const int* __restrict__ rs_e,
    const int4* __restrict__ recs,
    const float* __restrict__ bvec, float* __restrict__ out) {
  const int node = (blockIdx.x * 256 + threadIdx.x) >> 6;
  const int lane = threadIdx.x & 63;
  if (node >= N_NODES) return;
  float n0 = 0.f, n1 = 0.f, n2 = 0.f, n3 = 0.f;
  float d0 = 0.f, d1 = 0.f, d2 = 0.f, d3 = 0.f;
  #pragma unroll
  for (int hf = 0; hf < 2; ++hf) {
    const int j0 = rs_s[hf * N_NODES + node], j1 = rs_e[hf * N_NODES + node];
    #pragma unroll 8
    for (int j = j0; j < j1; ++j) {
      int4 rec = recs[j];               // 16B wave-uniform broadcast
      union { int i; __half2 h; } u01, u23;
      u01.i = rec.y; u23.i = rec.z;
      float2 f01 = __half22float2(u01.h);
      float2 f23 = __half22float2(u23.h);
      float xv = x[rec.x * 64 + lane];  // coalesced 256B gather
      d0 += f01.x; d1 += f01.y; d2 += f23.x; d3 += f23.y;
      n0 = fmaf(f01.x, xv, n0); n1 = fmaf(f01.y, xv, n1);
      n2 = fmaf(f23.x, xv, n2); n3 = fmaf(f23.y, xv, n3);
    }
  }
  float bv = bvec[lane];
  size_t ob = (size_t)node * 256 + lane;
  float o;
  o = n0 / fmaxf(d0, 1e-12f) + bv; o = (o > 0.f) ? o : (__expf(o) - 1.f); out[ob      ] = o;
  o = n1 / fmaxf(d1, 1e-12f) + bv; o = (o > 0.f) ? o : (__expf(o) - 1.f); out[ob +  64] = o;
  o = n2 / fmaxf(d2, 1e-12f) + bv; o = (o > 0.f) ? o : (__expf(o) - 1.f); out[ob + 128] = o;
  o = n3 / fmaxf(d3, 1e-12f) + bv; o = (o > 0.f) ? o : (__expf(o) - 1.f); out[ob + 192] = o;
}

// ---------------- Launch ----------------------------------------------------
extern "C" void kernel_launch(void* const* d_in, const int* in_sizes, int n_in,
                              void* d_out, int out_size, void* d_ws, size_t ws_size,
                              hipStream_t stream) {
  const float* h  = (const float*)d_in[0];
  const float* W  = (const float*)d_in[1];
  const float* Wl = (const float*)d_in[2];
  const float* Wr = (const float*)d_in[3];
  const float* b  = (const float*)d_in[4];
  const int*   ei = (const int*)d_in[5];
  float* out = (float*)d_out;   // reference output dtype is float32

  char* ws = (char*)d_ws;
  float*        x    = (float*)       (ws + 0);          // 12,800,000
  float*        el   = (float*)       (ws + 12800000);   //    800,000
  float*        er   = (float*)       (ws + 13600000);   //    800,000
  int*          bcnt = (int*)         (ws + 14400000);   // 8000*64  =    512,000
  unsigned int* raw  = (unsigned int*)(ws + 14912000);   // 8000*320*4 = 10,240,000
  int4*         recs = (int4*)        (ws + 25152000);   // 2000*1280*16 = 40,960,000
  int*          rs_s = (int*)         (ws + 66112000);   //    400,000
  int*          rs_e = (int*)         (ws + 66512000);   //    400,000  (end ~66.9 MB)
  (void)ws_size; (void)in_sizes; (void)n_in; (void)out_size;

  hipMemsetAsync(bcnt, 0, 512000, stream);

  k_x      <<<782,   256, 0, stream>>>(h, W, x);
  k_eler   <<<782,   256, 0, stream>>>(x, Wl, Wr, el, er);
  k_part   <<<6250,  256, 0, stream>>>(ei, bcnt, raw);
  k_bucket <<<2000,  256, 0, stream>>>(raw, bcnt, el, er, recs, rs_s, rs_e);
  k_agg    <<<12500, 256, 0, stream>>>(x, rs_s, rs_e, recs, b, out);
}

// Round 3
// 312.483 us; speedup vs baseline: 1.1022x; 1.0884x over previous
//
#include <hip/hip_runtime.h>
#include <hip/hip_bf16.h>
#include <hip/hip_fp16.h>

#define N_NODES 50000
#define N_EDGES 1600000
#define NPB    50      // nodes per bucket
#define NBUK   1000    // NPB*NBUK == N_NODES
#define NSL    8       // XCD slices
#define BCAPS  320     // slots per (bucket,slice): mean 200, +8.5 sigma
#define BCAPH  1280    // 4*BCAPS, per bucket-half

typedef __attribute__((ext_vector_type(8))) short short8;
typedef __attribute__((ext_vector_type(4))) float f32x4;

__device__ __forceinline__ unsigned short f2bf(float f) {
  union { float f; unsigned int i; } v; v.f = f;
  unsigned int i = v.i;
  unsigned int r = i + 0x7FFFu + ((i >> 16) & 1u);
  return (unsigned short)(r >> 16);
}

// ---------------- Kernel 1: x = h @ W  (fp32 in, bf16 MFMA, f32 out) -------
__global__ __launch_bounds__(256) void k_x(const float* __restrict__ hmat,
                                           const float* __restrict__ Wmat,
                                           float* __restrict__ x) {
  __shared__ unsigned short Wt[64 * 264];  // Wt[n][k], row stride 264 (16B-aligned)
  const int t = threadIdx.x;
  for (int idx = t; idx < 64 * 256; idx += 256) {
    int k = idx >> 6, n = idx & 63;        // global read coalesced (idx = k*64+n)
    Wt[n * 264 + k] = f2bf(Wmat[idx]);
  }
  __syncthreads();
  const int wave = t >> 6, lane = t & 63;
  const int quad = lane >> 4, l16 = lane & 15;
  const int m0 = blockIdx.x * 64 + wave * 16;
  int arow = m0 + l16; if (arow >= N_NODES) arow = N_NODES - 1;  // clamp: rows independent
  f32x4 c[4] = {{0,0,0,0},{0,0,0,0},{0,0,0,0},{0,0,0,0}};
  const float* aptr = hmat + (size_t)arow * 256 + quad * 8;
  #pragma unroll
  for (int kb = 0; kb < 8; ++kb) {
    f32x4 a0 = *(const f32x4*)(aptr + kb * 32);
    f32x4 a1 = *(const f32x4*)(aptr + kb * 32 + 4);
    short8 a;
    a[0] = (short)f2bf(a0[0]); a[1] = (short)f2bf(a0[1]);
    a[2] = (short)f2bf(a0[2]); a[3] = (short)f2bf(a0[3]);
    a[4] = (short)f2bf(a1[0]); a[5] = (short)f2bf(a1[1]);
    a[6] = (short)f2bf(a1[2]); a[7] = (short)f2bf(a1[3]);
    #pragma unroll
    for (int nt = 0; nt < 4; ++nt) {
      int n = nt * 16 + l16;
      short8 b = *(const short8*)(&Wt[n * 264 + kb * 32 + quad * 8]);
      c[nt] = __builtin_amdgcn_mfma_f32_16x16x32_bf16(a, b, c[nt], 0, 0, 0);
    }
  }
  #pragma unroll
  for (int nt = 0; nt < 4; ++nt) {
    #pragma unroll
    for (int r = 0; r < 4; ++r) {
      int grow = m0 + quad * 4 + r;
      if (grow < N_NODES) x[grow * 64 + nt * 16 + l16] = c[nt][r];
    }
  }
}

// ---------------- Kernel 2: el = x@Wl^T, er = x@Wr^T (wave per row) ---------
// Also emits the fp16 copy of x used by k_agg's gather (halves gather bytes,
// 6.4MB footprint caches ~2x better in per-XCD L2 than 12.8MB fp32).
__global__ __launch_bounds__(256) void k_eler(const float* __restrict__ x,
    const float* __restrict__ Wl, const float* __restrict__ Wr,
    float* __restrict__ el, float* __restrict__ er,
    __half* __restrict__ x16) {
  const int lane = threadIdx.x & 63;
  const int gw = (blockIdx.x * 256 + threadIdx.x) >> 6;
  const int nw = gridDim.x * 4;
  float wl[4], wr[4];
  #pragma unroll
  for (int hh = 0; hh < 4; ++hh) {
    wl[hh] = Wl[hh * 64 + lane];
    wr[hh] = Wr[hh * 64 + lane];
  }
  for (int r = gw; r < N_NODES; r += nw) {
    float xv = x[r * 64 + lane];
    x16[r * 64 + lane] = __float2half(xv);   // coalesced 128B/row store
    float p[4], q[4];
    #pragma unroll
    for (int hh = 0; hh < 4; ++hh) { p[hh] = xv * wl[hh]; q[hh] = xv * wr[hh]; }
    #pragma unroll
    for (int off = 32; off > 0; off >>= 1) {
      #pragma unroll
      for (int hh = 0; hh < 4; ++hh) {
        p[hh] += __shfl_xor(p[hh], off, 64);
        q[hh] += __shfl_xor(q[hh], off, 64);
      }
    }
    if (lane == 0) {
      f32x4 pv = {p[0], p[1], p[2], p[3]};
      f32x4 qv = {q[0], q[1], q[2], q[3]};
      ((f32x4*)el)[r] = pv;
      ((f32x4*)er)[r] = qv;
    }
  }
}

// ---------------- Kernel 3: XCD-sliced bucket partition ---------------------
// slice = blockIdx&7 ~ XCD id (round-robin dispatch heuristic). Each
// (bucket,slice) sub-list is filled by one XCD only -> lines written once,
// cursor atomics XCD-local with 8x less contention.
__global__ __launch_bounds__(256) void k_part(const int* __restrict__ ei,
                                              int* __restrict__ bcnt,
                                              unsigned int* __restrict__ raw) {
  int e = blockIdx.x * 256 + threadIdx.x;
  int slice = blockIdx.x & 7;
  if (e < N_EDGES) {
    int s = ei[e], d = ei[N_EDGES + e];
    int b  = s / NPB;
    int sl = s - b * NPB;
    int cell = b * NSL + slice;
    int pos = atomicAdd(&bcnt[cell * 16], 1);
    if (pos < BCAPS)
      raw[(size_t)cell * BCAPS + pos] = ((unsigned int)d << 8) | (unsigned int)sl;
  }
}

// ---------------- Kernel 4: per-bucket-half CSR + edge weights --------------
// Grid 2000: b = blk>>1, half = blk&1 handles slices 4*half..4*half+3.
__global__ __launch_bounds__(256) void k_bucket(const unsigned int* __restrict__ raw,
    const int* __restrict__ bcnt,
    const float* __restrict__ el, const float* __restrict__ er,
    int4* __restrict__ recs, int* __restrict__ rs_s, int* __restrict__ rs_e) {
  __shared__ unsigned int sraw[BCAPH];
  __shared__ int pref[NPB + 1];
  __shared__ int cur[NPB];
  const int b = blockIdx.x >> 1, H = blockIdx.x & 1, t = threadIdx.x;
  const int s0 = H * 4;
  int c0 = bcnt[(b * NSL + s0 + 0) * 16]; if (c0 > BCAPS) c0 = BCAPS;
  int c1 = bcnt[(b * NSL + s0 + 1) * 16]; if (c1 > BCAPS) c1 = BCAPS;
  int c2 = bcnt[(b * NSL + s0 + 2) * 16]; if (c2 > BCAPS) c2 = BCAPS;
  int c3 = bcnt[(b * NSL + s0 + 3) * 16]; if (c3 > BCAPS) c3 = BCAPS;
  const int o1 = c0, o2 = c0 + c1, o3 = c0 + c1 + c2, cnt = o3 + c3;
  if (t <= NPB) pref[t] = 0;
  __syncthreads();
  for (int j = t; j < c0; j += 256) { unsigned int r = raw[(size_t)(b*NSL+s0+0)*BCAPS + j]; sraw[j]      = r; atomicAdd(&pref[(int)(r & 255u) + 1], 1); }
  for (int j = t; j < c1; j += 256) { unsigned int r = raw[(size_t)(b*NSL+s0+1)*BCAPS + j]; sraw[o1 + j] = r; atomicAdd(&pref[(int)(r & 255u) + 1], 1); }
  for (int j = t; j < c2; j += 256) { unsigned int r = raw[(size_t)(b*NSL+s0+2)*BCAPS + j]; sraw[o2 + j] = r; atomicAdd(&pref[(int)(r & 255u) + 1], 1); }
  for (int j = t; j < c3; j += 256) { unsigned int r = raw[(size_t)(b*NSL+s0+3)*BCAPS + j]; sraw[o3 + j] = r; atomicAdd(&pref[(int)(r & 255u) + 1], 1); }
  __syncthreads();
  if (t == 0) {
    int run = 0;
    #pragma unroll
    for (int n = 0; n <= NPB; ++n) { run += pref[n]; pref[n] = run; }
  }
  __syncthreads();
  const int wbase = (b * 2 + H) * BCAPH;   // this half's window in recs
  if (t < NPB) {
    cur[t] = pref[t];
    rs_s[H * N_NODES + b * NPB + t] = wbase + pref[t];
    rs_e[H * N_NODES + b * NPB + t] = wbase + pref[t + 1];
  }
  __syncthreads();
  const int base = b * NPB;
  for (int j = t; j < cnt; j += 256) {
    unsigned int r = sraw[j];
    int sl = (int)(r & 255u);
    int d  = (int)(r >> 8);
    int pos = atomicAdd(&cur[sl], 1);
    f32x4 a = ((const f32x4*)el)[base + sl];   // L1-resident (800B/bucket)
    f32x4 e = ((const f32x4*)er)[d];           // L2-resident (800 KB)
    float w[4];
    #pragma unroll
    for (int hh = 0; hh < 4; ++hh) {
      float tt = a[hh] + e[hh];
      tt = (tt >= 0.f) ? tt : 0.2f * tt;
      w[hh] = __expf(tt);
    }
    union { __half2 h; int i; } u01, u23;
    u01.h = __floats2half2_rn(w[0], w[1]);
    u23.h = __floats2half2_rn(w[2], w[3]);
    int4 rc; rc.x = d; rc.y = u01.i; rc.z = u23.i; rc.w = 0;
    recs[(size_t)wbase + pos] = rc;            // scattered within 20KB window
  }
}

// ---------------- Kernel 5: fused normalize + SpMM + ELU --------------------
// One wave per node; per-node edges live in two half-ranges.
// Known-good unroll-4 schedule (82us) — do NOT restructure this loop; both the
// shfl-broadcast and unroll-8 variants regressed (107/106us). Gather reads the
// fp16 x copy: half the bytes, ~2x better XCD-L2 residency.
__global__ __launch_bounds__(256) void k_agg(const __half* __restrict__ x16,
    const int* __restrict__ rs_s, const int* __restrict__ rs_e,
    const int4* __restrict__ recs,
    const float* __restrict__ bvec, float* __restrict__ out) {
  const int node = (blockIdx.x * 256 + threadIdx.x) >> 6;
  const int lane = threadIdx.x & 63;
  if (node >= N_NODES) return;
  float n0 = 0.f, n1 = 0.f, n2 = 0.f, n3 = 0.f;
  float d0 = 0.f, d1 = 0.f, d2 = 0.f, d3 = 0.f;
  #pragma unroll
  for (int hf = 0; hf < 2; ++hf) {
    const int j0 = rs_s[hf * N_NODES + node], j1 = rs_e[hf * N_NODES + node];
    #pragma unroll 4
    for (int j = j0; j < j1; ++j) {
      int4 rec = recs[j];               // 16B wave-uniform broadcast
      union { int i; __half2 h; } u01, u23;
      u01.i = rec.y; u23.i = rec.z;
      float2 f01 = __half22float2(u01.h);
      float2 f23 = __half22float2(u23.h);
      float xv = __half2float(x16[(size_t)rec.x * 64 + lane]);  // coalesced 128B gather
      d0 += f01.x; d1 += f01.y; d2 += f23.x; d3 += f23.y;
      n0 = fmaf(f01.x, xv, n0); n1 = fmaf(f01.y, xv, n1);
      n2 = fmaf(f23.x, xv, n2); n3 = fmaf(f23.y, xv, n3);
    }
  }
  float bv = bvec[lane];
  size_t ob = (size_t)node * 256 + lane;
  float o;
  o = n0 / fmaxf(d0, 1e-12f) + bv; o = (o > 0.f) ? o : (__expf(o) - 1.f); out[ob      ] = o;
  o = n1 / fmaxf(d1, 1e-12f) + bv; o = (o > 0.f) ? o : (__expf(o) - 1.f); out[ob +  64] = o;
  o = n2 / fmaxf(d2, 1e-12f) + bv; o = (o > 0.f) ? o : (__expf(o) - 1.f); out[ob + 128] = o;
  o = n3 / fmaxf(d3, 1e-12f) + bv; o = (o > 0.f) ? o : (__expf(o) - 1.f); out[ob + 192] = o;
}

// ---------------- Launch ----------------------------------------------------
extern "C" void kernel_launch(void* const* d_in, const int* in_sizes, int n_in,
                              void* d_out, int out_size, void* d_ws, size_t ws_size,
                              hipStream_t stream) {
  const float* h  = (const float*)d_in[0];
  const float* W  = (const float*)d_in[1];
  const float* Wl = (const float*)d_in[2];
  const float* Wr = (const float*)d_in[3];
  const float* b  = (const float*)d_in[4];
  const int*   ei = (const int*)d_in[5];
  float* out = (float*)d_out;   // reference output dtype is float32

  char* ws = (char*)d_ws;
  float*        x    = (float*)       (ws + 0);          // 12,800,000
  float*        el   = (float*)       (ws + 12800000);   //    800,000
  float*        er   = (float*)       (ws + 13600000);   //    800,000
  int*          bcnt = (int*)         (ws + 14400000);   // 8000*64  =    512,000
  unsigned int* raw  = (unsigned int*)(ws + 14912000);   // 8000*320*4 = 10,240,000
  int4*         recs = (int4*)        (ws + 25152000);   // 2000*1280*16 = 40,960,000
  int*          rs_s = (int*)         (ws + 66112000);   //    400,000
  int*          rs_e = (int*)         (ws + 66512000);   //    400,000
  __half*       x16  = (__half*)      (ws + 66912000);   //  6,400,000  (end ~73.3 MB)
  (void)ws_size; (void)in_sizes; (void)n_in; (void)out_size;

  hipMemsetAsync(bcnt, 0, 512000, stream);

  k_x      <<<782,   256, 0, stream>>>(h, W, x);
  k_eler   <<<782,   256, 0, stream>>>(x, Wl, Wr, el, er, x16);
  k_part   <<<6250,  256, 0, stream>>>(ei, bcnt, raw);
  k_bucket <<<2000,  256, 0, stream>>>(raw, bcnt, el, er, recs, rs_s, rs_e);
  k_agg    <<<12500, 256, 0, stream>>>(x16, rs_s, rs_e, recs, b, out);
}

// Round 4
// 304.998 us; speedup vs baseline: 1.1292x; 1.0245x over previous
//
#include <hip/hip_runtime.h>
#include <hip/hip_bf16.h>
#include <hip/hip_fp16.h>

#define N_NODES 50000
#define N_EDGES 1600000
#define NPB    50      // nodes per bucket
#define NBUK   1000    // NPB*NBUK == N_NODES
#define NSL    8       // XCD slices
#define BCAPS  320     // slots per (bucket,slice): mean 200, +8.5 sigma
#define BCAPH  1280    // 4*BCAPS, per bucket-half

typedef __attribute__((ext_vector_type(8))) short short8;
typedef __attribute__((ext_vector_type(4))) float f32x4;

__device__ __forceinline__ unsigned short f2bf(float f) {
  union { float f; unsigned int i; } v; v.f = f;
  unsigned int i = v.i;
  unsigned int r = i + 0x7FFFu + ((i >> 16) & 1u);
  return (unsigned short)(r >> 16);
}

// ---------------- Kernel 1: x = h @ W  (fp32 in, bf16 MFMA, f32 out) -------
__global__ __launch_bounds__(256) void k_x(const float* __restrict__ hmat,
                                           const float* __restrict__ Wmat,
                                           float* __restrict__ x) {
  __shared__ unsigned short Wt[64 * 264];  // Wt[n][k], row stride 264 (16B-aligned)
  const int t = threadIdx.x;
  for (int idx = t; idx < 64 * 256; idx += 256) {
    int k = idx >> 6, n = idx & 63;        // global read coalesced (idx = k*64+n)
    Wt[n * 264 + k] = f2bf(Wmat[idx]);
  }
  __syncthreads();
  const int wave = t >> 6, lane = t & 63;
  const int quad = lane >> 4, l16 = lane & 15;
  const int m0 = blockIdx.x * 64 + wave * 16;
  int arow = m0 + l16; if (arow >= N_NODES) arow = N_NODES - 1;  // clamp: rows independent
  f32x4 c[4] = {{0,0,0,0},{0,0,0,0},{0,0,0,0},{0,0,0,0}};
  const float* aptr = hmat + (size_t)arow * 256 + quad * 8;
  #pragma unroll
  for (int kb = 0; kb < 8; ++kb) {
    f32x4 a0 = *(const f32x4*)(aptr + kb * 32);
    f32x4 a1 = *(const f32x4*)(aptr + kb * 32 + 4);
    short8 a;
    a[0] = (short)f2bf(a0[0]); a[1] = (short)f2bf(a0[1]);
    a[2] = (short)f2bf(a0[2]); a[3] = (short)f2bf(a0[3]);
    a[4] = (short)f2bf(a1[0]); a[5] = (short)f2bf(a1[1]);
    a[6] = (short)f2bf(a1[2]); a[7] = (short)f2bf(a1[3]);
    #pragma unroll
    for (int nt = 0; nt < 4; ++nt) {
      int n = nt * 16 + l16;
      short8 b = *(const short8*)(&Wt[n * 264 + kb * 32 + quad * 8]);
      c[nt] = __builtin_amdgcn_mfma_f32_16x16x32_bf16(a, b, c[nt], 0, 0, 0);
    }
  }
  #pragma unroll
  for (int nt = 0; nt < 4; ++nt) {
    #pragma unroll
    for (int r = 0; r < 4; ++r) {
      int grow = m0 + quad * 4 + r;
      if (grow < N_NODES) x[grow * 64 + nt * 16 + l16] = c[nt][r];
    }
  }
}

// ---------------- Kernel 2: el = x@Wl^T, er = x@Wr^T (wave per row) ---------
// Also emits the fp16 copy of x used by k_agg's gather (halves gather bytes,
// 6.4MB footprint caches ~2x better in per-XCD L2 than 12.8MB fp32).
__global__ __launch_bounds__(256) void k_eler(const float* __restrict__ x,
    const float* __restrict__ Wl, const float* __restrict__ Wr,
    float* __restrict__ el, float* __restrict__ er,
    __half* __restrict__ x16) {
  const int lane = threadIdx.x & 63;
  const int gw = (blockIdx.x * 256 + threadIdx.x) >> 6;
  const int nw = gridDim.x * 4;
  float wl[4], wr[4];
  #pragma unroll
  for (int hh = 0; hh < 4; ++hh) {
    wl[hh] = Wl[hh * 64 + lane];
    wr[hh] = Wr[hh * 64 + lane];
  }
  for (int r = gw; r < N_NODES; r += nw) {
    float xv = x[r * 64 + lane];
    x16[r * 64 + lane] = __float2half(xv);   // coalesced 128B/row store
    float p[4], q[4];
    #pragma unroll
    for (int hh = 0; hh < 4; ++hh) { p[hh] = xv * wl[hh]; q[hh] = xv * wr[hh]; }
    #pragma unroll
    for (int off = 32; off > 0; off >>= 1) {
      #pragma unroll
      for (int hh = 0; hh < 4; ++hh) {
        p[hh] += __shfl_xor(p[hh], off, 64);
        q[hh] += __shfl_xor(q[hh], off, 64);
      }
    }
    if (lane == 0) {
      f32x4 pv = {p[0], p[1], p[2], p[3]};
      f32x4 qv = {q[0], q[1], q[2], q[3]};
      ((f32x4*)el)[r] = pv;
      ((f32x4*)er)[r] = qv;
    }
  }
}

// ---------------- Kernel 3: XCD-sliced bucket partition ---------------------
// slice = blockIdx&7 ~ XCD id (round-robin dispatch heuristic). Each
// (bucket,slice) sub-list is filled by one XCD only -> lines written once,
// cursor atomics XCD-local with 8x less contention.
__global__ __launch_bounds__(256) void k_part(const int* __restrict__ ei,
                                              int* __restrict__ bcnt,
                                              unsigned int* __restrict__ raw) {
  int e = blockIdx.x * 256 + threadIdx.x;
  int slice = blockIdx.x & 7;
  if (e < N_EDGES) {
    int s = ei[e], d = ei[N_EDGES + e];
    int b  = s / NPB;
    int sl = s - b * NPB;
    int cell = b * NSL + slice;
    int pos = atomicAdd(&bcnt[cell * 16], 1);
    if (pos < BCAPS)
      raw[(size_t)cell * BCAPS + pos] = ((unsigned int)d << 8) | (unsigned int)sl;
  }
}

// ---------------- Kernel 4: per-bucket-half CSR + edge weights --------------
// Grid 2000: b = blk>>1, half = blk&1 handles slices 4*half..4*half+3.
__global__ __launch_bounds__(256) void k_bucket(const unsigned int* __restrict__ raw,
    const int* __restrict__ bcnt,
    const float* __restrict__ el, const float* __restrict__ er,
    int4* __restrict__ recs, int* __restrict__ rs_s, int* __restrict__ rs_e) {
  __shared__ unsigned int sraw[BCAPH];
  __shared__ int pref[NPB + 1];
  __shared__ int cur[NPB];
  const int b = blockIdx.x >> 1, H = blockIdx.x & 1, t = threadIdx.x;
  const int s0 = H * 4;
  int c0 = bcnt[(b * NSL + s0 + 0) * 16]; if (c0 > BCAPS) c0 = BCAPS;
  int c1 = bcnt[(b * NSL + s0 + 1) * 16]; if (c1 > BCAPS) c1 = BCAPS;
  int c2 = bcnt[(b * NSL + s0 + 2) * 16]; if (c2 > BCAPS) c2 = BCAPS;
  int c3 = bcnt[(b * NSL + s0 + 3) * 16]; if (c3 > BCAPS) c3 = BCAPS;
  const int o1 = c0, o2 = c0 + c1, o3 = c0 + c1 + c2, cnt = o3 + c3;
  if (t <= NPB) pref[t] = 0;
  __syncthreads();
  for (int j = t; j < c0; j += 256) { unsigned int r = raw[(size_t)(b*NSL+s0+0)*BCAPS + j]; sraw[j]      = r; atomicAdd(&pref[(int)(r & 255u) + 1], 1); }
  for (int j = t; j < c1; j += 256) { unsigned int r = raw[(size_t)(b*NSL+s0+1)*BCAPS + j]; sraw[o1 + j] = r; atomicAdd(&pref[(int)(r & 255u) + 1], 1); }
  for (int j = t; j < c2; j += 256) { unsigned int r = raw[(size_t)(b*NSL+s0+2)*BCAPS + j]; sraw[o2 + j] = r; atomicAdd(&pref[(int)(r & 255u) + 1], 1); }
  for (int j = t; j < c3; j += 256) { unsigned int r = raw[(size_t)(b*NSL+s0+3)*BCAPS + j]; sraw[o3 + j] = r; atomicAdd(&pref[(int)(r & 255u) + 1], 1); }
  __syncthreads();
  if (t == 0) {
    int run = 0;
    #pragma unroll
    for (int n = 0; n <= NPB; ++n) { run += pref[n]; pref[n] = run; }
  }
  __syncthreads();
  const int wbase = (b * 2 + H) * BCAPH;   // this half's window in recs
  if (t < NPB) {
    cur[t] = pref[t];
    rs_s[H * N_NODES + b * NPB + t] = wbase + pref[t];
    rs_e[H * N_NODES + b * NPB + t] = wbase + pref[t + 1];
  }
  __syncthreads();
  const int base = b * NPB;
  for (int j = t; j < cnt; j += 256) {
    unsigned int r = sraw[j];
    int sl = (int)(r & 255u);
    int d  = (int)(r >> 8);
    int pos = atomicAdd(&cur[sl], 1);
    f32x4 a = ((const f32x4*)el)[base + sl];   // L1-resident (800B/bucket)
    f32x4 e = ((const f32x4*)er)[d];           // L2-resident (800 KB)
    float w[4];
    #pragma unroll
    for (int hh = 0; hh < 4; ++hh) {
      float tt = a[hh] + e[hh];
      tt = (tt >= 0.f) ? tt : 0.2f * tt;
      w[hh] = __expf(tt);
    }
    union { __half2 h; int i; } u01, u23;
    u01.h = __floats2half2_rn(w[0], w[1]);
    u23.h = __floats2half2_rn(w[2], w[3]);
    int4 rc; rc.x = d; rc.y = u01.i; rc.z = u23.i; rc.w = 0;
    recs[(size_t)wbase + pos] = rc;            // scattered within 20KB window
  }
}

// ---------------- Kernel 5: fused normalize + SpMM + ELU --------------------
// One wave per node; unroll-4 schedule preserved (82us known-good; shfl and
// unroll-8 variants both regressed). NEW: j0/j1 hoisted to SGPR via
// readfirstlane -> recs[j] is provably wave-uniform -> s_load_dwordx4 on the
// SMEM pipe (no vector address math, rec fields land in SGPRs); gather becomes
// saddr-form global_load_ushort with the lane offset hoisted. Per-edge VALU
// ~25 -> ~13, everything uniform runs on SALU.
__global__ __launch_bounds__(256) void k_agg(const __half* __restrict__ x16,
    const int* __restrict__ rs_s, const int* __restrict__ rs_e,
    const int4* __restrict__ recs,
    const float* __restrict__ bvec, float* __restrict__ out) {
  const int node = (blockIdx.x * 256 + threadIdx.x) >> 6;
  const int lane = threadIdx.x & 63;
  if (node >= N_NODES) return;
  float n0 = 0.f, n1 = 0.f, n2 = 0.f, n3 = 0.f;
  float d0 = 0.f, d1 = 0.f, d2 = 0.f, d3 = 0.f;
  #pragma unroll
  for (int hf = 0; hf < 2; ++hf) {
    const int j0 = __builtin_amdgcn_readfirstlane(rs_s[hf * N_NODES + node]);
    const int j1 = __builtin_amdgcn_readfirstlane(rs_e[hf * N_NODES + node]);
    #pragma unroll 4
    for (int j = j0; j < j1; ++j) {
      int4 rec = recs[j];               // uniform addr -> s_load_dwordx4
      union { int i; __half2 h; } u01, u23;
      u01.i = rec.y; u23.i = rec.z;
      float2 f01 = __half22float2(u01.h);
      float2 f23 = __half22float2(u23.h);
      const __half* rowp = x16 + ((size_t)rec.x << 6);   // SGPR row base
      float xv = __half2float(rowp[lane]);               // saddr-form gather
      d0 += f01.x; d1 += f01.y; d2 += f23.x; d3 += f23.y;
      n0 = fmaf(f01.x, xv, n0); n1 = fmaf(f01.y, xv, n1);
      n2 = fmaf(f23.x, xv, n2); n3 = fmaf(f23.y, xv, n3);
    }
  }
  float bv = bvec[lane];
  size_t ob = (size_t)node * 256 + lane;
  float o;
  o = n0 / fmaxf(d0, 1e-12f) + bv; o = (o > 0.f) ? o : (__expf(o) - 1.f); out[ob      ] = o;
  o = n1 / fmaxf(d1, 1e-12f) + bv; o = (o > 0.f) ? o : (__expf(o) - 1.f); out[ob +  64] = o;
  o = n2 / fmaxf(d2, 1e-12f) + bv; o = (o > 0.f) ? o : (__expf(o) - 1.f); out[ob + 128] = o;
  o = n3 / fmaxf(d3, 1e-12f) + bv; o = (o > 0.f) ? o : (__expf(o) - 1.f); out[ob + 192] = o;
}

// ---------------- Launch ----------------------------------------------------
extern "C" void kernel_launch(void* const* d_in, const int* in_sizes, int n_in,
                              void* d_out, int out_size, void* d_ws, size_t ws_size,
                              hipStream_t stream) {
  const float* h  = (const float*)d_in[0];
  const float* W  = (const float*)d_in[1];
  const float* Wl = (const float*)d_in[2];
  const float* Wr = (const float*)d_in[3];
  const float* b  = (const float*)d_in[4];
  const int*   ei = (const int*)d_in[5];
  float* out = (float*)d_out;   // reference output dtype is float32

  char* ws = (char*)d_ws;
  float*        x    = (float*)       (ws + 0);          // 12,800,000
  float*        el   = (float*)       (ws + 12800000);   //    800,000
  float*        er   = (float*)       (ws + 13600000);   //    800,000
  int*          bcnt = (int*)         (ws + 14400000);   // 8000*64  =    512,000
  unsigned int* raw  = (unsigned int*)(ws + 14912000);   // 8000*320*4 = 10,240,000
  int4*         recs = (int4*)        (ws + 25152000);   // 2000*1280*16 = 40,960,000
  int*          rs_s = (int*)         (ws + 66112000);   //    400,000
  int*          rs_e = (int*)         (ws + 66512000);   //    400,000
  __half*       x16  = (__half*)      (ws + 66912000);   //  6,400,000  (end ~73.3 MB)
  (void)ws_size; (void)in_sizes; (void)n_in; (void)out_size;

  hipMemsetAsync(bcnt, 0, 512000, stream);

  k_x      <<<782,   256, 0, stream>>>(h, W, x);
  k_eler   <<<782,   256, 0, stream>>>(x, Wl, Wr, el, er, x16);
  k_part   <<<6250,  256, 0, stream>>>(ei, bcnt, raw);
  k_bucket <<<2000,  256, 0, stream>>>(raw, bcnt, el, er, recs, rs_s, rs_e);
  k_agg    <<<12500, 256, 0, stream>>>(x16, rs_s, rs_e, recs, b, out);
}

// Round 5
// 263.336 us; speedup vs baseline: 1.3079x; 1.1582x over previous
//
#include <hip/hip_runtime.h>
#include <hip/hip_bf16.h>
#include <hip/hip_fp16.h>

#define N_NODES 50000
#define N_EDGES 1600000
#define NPB    50      // nodes per bucket
#define NBUK   1000    // NPB*NBUK == N_NODES
#define NSL    8       // XCD slices
#define BCAPS  320     // slots per (bucket,slice): mean 200, +8.5 sigma
#define BCAPH  1280    // 4*BCAPS, per bucket-half
#define GEMMB  782     // GEMM blocks in fused kernel
#define PARTB  256     // partition blocks in fused kernel
#define CHUNK  6250    // edges per partition block (256*6250 = 1.6M)
#define BD     10      // LDS bin depth (lambda=6.25, overflow ~0.5% -> fallback)

typedef __attribute__((ext_vector_type(8))) short short8;
typedef __attribute__((ext_vector_type(4))) float f32x4;

__device__ __forceinline__ unsigned short f2bf(float f) {
  union { float f; unsigned int i; } v; v.f = f;
  unsigned int i = v.i;
  unsigned int r = i + 0x7FFFu + ((i >> 16) & 1u);
  return (unsigned short)(r >> 16);
}

// ---------------- Kernel 1: FUSED  x = h @ W  +  edge partition -------------
// Blocks [0,782): bf16-MFMA GEMM (byte-identical math to previous k_x).
// Blocks [782,1038): LDS-binned edge partition. The two chains are data-
// independent (GEMM: h,W -> x; part: ei -> raw,bcnt), so fusing lets the
// latency-bound atomic work hide under the MFMA/LDS-bound GEMM waves.
// Shared LDS union: GEMM 33.8KB, part 44.0KB -> 44KB static, 3 blocks/CU
// either way (GEMM had 782 blocks ~3/CU before; no occupancy loss).
__global__ __launch_bounds__(256) void k_xpart(const float* __restrict__ hmat,
    const float* __restrict__ Wmat, float* __restrict__ x,
    const int* __restrict__ ei, int* __restrict__ bcnt,
    unsigned int* __restrict__ raw) {
  __shared__ __align__(16) char smem[44032];
  const int t = threadIdx.x;
  if (blockIdx.x < GEMMB) {
    // ---- GEMM path (unchanged) ----
    unsigned short* Wt = (unsigned short*)smem;   // Wt[n][k], row stride 264
    for (int idx = t; idx < 64 * 256; idx += 256) {
      int k = idx >> 6, n = idx & 63;
      Wt[n * 264 + k] = f2bf(Wmat[idx]);
    }
    __syncthreads();
    const int wave = t >> 6, lane = t & 63;
    const int quad = lane >> 4, l16 = lane & 15;
    const int m0 = blockIdx.x * 64 + wave * 16;
    int arow = m0 + l16; if (arow >= N_NODES) arow = N_NODES - 1;
    f32x4 c[4] = {{0,0,0,0},{0,0,0,0},{0,0,0,0},{0,0,0,0}};
    const float* aptr = hmat + (size_t)arow * 256 + quad * 8;
    #pragma unroll
    for (int kb = 0; kb < 8; ++kb) {
      f32x4 a0 = *(const f32x4*)(aptr + kb * 32);
      f32x4 a1 = *(const f32x4*)(aptr + kb * 32 + 4);
      short8 a;
      a[0] = (short)f2bf(a0[0]); a[1] = (short)f2bf(a0[1]);
      a[2] = (short)f2bf(a0[2]); a[3] = (short)f2bf(a0[3]);
      a[4] = (short)f2bf(a1[0]); a[5] = (short)f2bf(a1[1]);
      a[6] = (short)f2bf(a1[2]); a[7] = (short)f2bf(a1[3]);
      #pragma unroll
      for (int nt = 0; nt < 4; ++nt) {
        int n = nt * 16 + l16;
        short8 b = *(const short8*)(&Wt[n * 264 + kb * 32 + quad * 8]);
        c[nt] = __builtin_amdgcn_mfma_f32_16x16x32_bf16(a, b, c[nt], 0, 0, 0);
      }
    }
    #pragma unroll
    for (int nt = 0; nt < 4; ++nt) {
      #pragma unroll
      for (int r = 0; r < 4; ++r) {
        int grow = m0 + quad * 4 + r;
        if (grow < N_NODES) x[grow * 64 + nt * 16 + l16] = c[nt][r];
      }
    }
  } else {
    // ---- LDS-binned partition path ----
    int* scnt = (int*)smem;                          // [1000] counters (4KB)
    unsigned int* sbin = (unsigned int*)(smem + 4000); // [1000][BD] bins (40KB)
    const int pj = blockIdx.x - GEMMB;
    const int slice = blockIdx.x & 7;                // XCD-local cell, as before
    for (int i = t; i < NBUK; i += 256) scnt[i] = 0;
    __syncthreads();
    const int e0 = pj * CHUNK;
    for (int e = e0 + t; e < e0 + CHUNK; e += 256) {
      int s = ei[e], d = ei[N_EDGES + e];
      int b = s / NPB;
      int sl = s - b * NPB;
      unsigned int val = ((unsigned int)d << 8) | (unsigned int)sl;
      int p = atomicAdd(&scnt[b], 1);                // LDS atomic (cheap)
      if (p < BD) {
        sbin[b * BD + p] = val;
      } else {                                       // rare overflow: old path
        int cell = b * NSL + slice;
        int gp = atomicAdd(&bcnt[cell * 16], 1);
        if (gp < BCAPS) raw[(size_t)cell * BCAPS + gp] = val;
      }
    }
    __syncthreads();
    // flush: ONE global atomic per non-empty (block,bucket); contiguous run
    for (int b = t; b < NBUK; b += 256) {
      int c = scnt[b]; if (c > BD) c = BD;
      if (c > 0) {
        int cell = b * NSL + slice;
        int gp = atomicAdd(&bcnt[cell * 16], c);
        for (int k = 0; k < c; ++k) {
          int idx = gp + k;
          if (idx < BCAPS) raw[(size_t)cell * BCAPS + idx] = sbin[b * BD + k];
        }
      }
    }
  }
}

// ---------------- Kernel 2: el = x@Wl^T, er = x@Wr^T (wave per row) ---------
// Also emits the fp16 copy of x used by k_agg's gather (halves gather bytes,
// 6.4MB footprint caches ~2x better in per-XCD L2 than 12.8MB fp32).
__global__ __launch_bounds__(256) void k_eler(const float* __restrict__ x,
    const float* __restrict__ Wl, const float* __restrict__ Wr,
    float* __restrict__ el, float* __restrict__ er,
    __half* __restrict__ x16) {
  const int lane = threadIdx.x & 63;
  const int gw = (blockIdx.x * 256 + threadIdx.x) >> 6;
  const int nw = gridDim.x * 4;
  float wl[4], wr[4];
  #pragma unroll
  for (int hh = 0; hh < 4; ++hh) {
    wl[hh] = Wl[hh * 64 + lane];
    wr[hh] = Wr[hh * 64 + lane];
  }
  for (int r = gw; r < N_NODES; r += nw) {
    float xv = x[r * 64 + lane];
    x16[r * 64 + lane] = __float2half(xv);   // coalesced 128B/row store
    float p[4], q[4];
    #pragma unroll
    for (int hh = 0; hh < 4; ++hh) { p[hh] = xv * wl[hh]; q[hh] = xv * wr[hh]; }
    #pragma unroll
    for (int off = 32; off > 0; off >>= 1) {
      #pragma unroll
      for (int hh = 0; hh < 4; ++hh) {
        p[hh] += __shfl_xor(p[hh], off, 64);
        q[hh] += __shfl_xor(q[hh], off, 64);
      }
    }
    if (lane == 0) {
      f32x4 pv = {p[0], p[1], p[2], p[3]};
      f32x4 qv = {q[0], q[1], q[2], q[3]};
      ((f32x4*)el)[r] = pv;
      ((f32x4*)er)[r] = qv;
    }
  }
}

// ---------------- Kernel 4: per-bucket-half CSR + edge weights --------------
// Grid 2000: b = blk>>1, half = blk&1 handles slices 4*half..4*half+3.
__global__ __launch_bounds__(256) void k_bucket(const unsigned int* __restrict__ raw,
    const int* __restrict__ bcnt,
    const float* __restrict__ el, const float* __restrict__ er,
    int4* __restrict__ recs, int* __restrict__ rs_s, int* __restrict__ rs_e) {
  __shared__ unsigned int sraw[BCAPH];
  __shared__ int pref[NPB + 1];
  __shared__ int cur[NPB];
  const int b = blockIdx.x >> 1, H = blockIdx.x & 1, t = threadIdx.x;
  const int s0 = H * 4;
  int c0 = bcnt[(b * NSL + s0 + 0) * 16]; if (c0 > BCAPS) c0 = BCAPS;
  int c1 = bcnt[(b * NSL + s0 + 1) * 16]; if (c1 > BCAPS) c1 = BCAPS;
  int c2 = bcnt[(b * NSL + s0 + 2) * 16]; if (c2 > BCAPS) c2 = BCAPS;
  int c3 = bcnt[(b * NSL + s0 + 3) * 16]; if (c3 > BCAPS) c3 = BCAPS;
  const int o1 = c0, o2 = c0 + c1, o3 = c0 + c1 + c2, cnt = o3 + c3;
  if (t <= NPB) pref[t] = 0;
  __syncthreads();
  for (int j = t; j < c0; j += 256) { unsigned int r = raw[(size_t)(b*NSL+s0+0)*BCAPS + j]; sraw[j]      = r; atomicAdd(&pref[(int)(r & 255u) + 1], 1); }
  for (int j = t; j < c1; j += 256) { unsigned int r = raw[(size_t)(b*NSL+s0+1)*BCAPS + j]; sraw[o1 + j] = r; atomicAdd(&pref[(int)(r & 255u) + 1], 1); }
  for (int j = t; j < c2; j += 256) { unsigned int r = raw[(size_t)(b*NSL+s0+2)*BCAPS + j]; sraw[o2 + j] = r; atomicAdd(&pref[(int)(r & 255u) + 1], 1); }
  for (int j = t; j < c3; j += 256) { unsigned int r = raw[(size_t)(b*NSL+s0+3)*BCAPS + j]; sraw[o3 + j] = r; atomicAdd(&pref[(int)(r & 255u) + 1], 1); }
  __syncthreads();
  if (t == 0) {
    int run = 0;
    #pragma unroll
    for (int n = 0; n <= NPB; ++n) { run += pref[n]; pref[n] = run; }
  }
  __syncthreads();
  const int wbase = (b * 2 + H) * BCAPH;   // this half's window in recs
  if (t < NPB) {
    cur[t] = pref[t];
    rs_s[H * N_NODES + b * NPB + t] = wbase + pref[t];
    rs_e[H * N_NODES + b * NPB + t] = wbase + pref[t + 1];
  }
  __syncthreads();
  const int base = b * NPB;
  for (int j = t; j < cnt; j += 256) {
    unsigned int r = sraw[j];
    int sl = (int)(r & 255u);
    int d  = (int)(r >> 8);
    int pos = atomicAdd(&cur[sl], 1);
    f32x4 a = ((const f32x4*)el)[base + sl];   // L1-resident (800B/bucket)
    f32x4 e = ((const f32x4*)er)[d];           // L2-resident (800 KB)
    float w[4];
    #pragma unroll
    for (int hh = 0; hh < 4; ++hh) {
      float tt = a[hh] + e[hh];
      tt = (tt >= 0.f) ? tt : 0.2f * tt;
      w[hh] = __expf(tt);
    }
    union { __half2 h; int i; } u01, u23;
    u01.h = __floats2half2_rn(w[0], w[1]);
    u23.h = __floats2half2_rn(w[2], w[3]);
    int4 rc; rc.x = d; rc.y = u01.i; rc.z = u23.i; rc.w = 0;
    recs[(size_t)wbase + pos] = rc;            // scattered within 20KB window
  }
}

// ---------------- Kernel 5: fused normalize + SpMM + ELU --------------------
// One wave per node; unroll-4 schedule preserved (known-good); j0/j1 hoisted
// to SGPR via readfirstlane -> recs[j] wave-uniform (s_load path), gather is
// saddr-form with SGPR row base. Do NOT restructure this loop.
__global__ __launch_bounds__(256) void k_agg(const __half* __restrict__ x16,
    const int* __restrict__ rs_s, const int* __restrict__ rs_e,
    const int4* __restrict__ recs,
    const float* __restrict__ bvec, float* __restrict__ out) {
  const int node = (blockIdx.x * 256 + threadIdx.x) >> 6;
  const int lane = threadIdx.x & 63;
  if (node >= N_NODES) return;
  float n0 = 0.f, n1 = 0.f, n2 = 0.f, n3 = 0.f;
  float d0 = 0.f, d1 = 0.f, d2 = 0.f, d3 = 0.f;
  #pragma unroll
  for (int hf = 0; hf < 2; ++hf) {
    const int j0 = __builtin_amdgcn_readfirstlane(rs_s[hf * N_NODES + node]);
    const int j1 = __builtin_amdgcn_readfirstlane(rs_e[hf * N_NODES + node]);
    #pragma unroll 4
    for (int j = j0; j < j1; ++j) {
      int4 rec = recs[j];               // uniform addr -> s_load_dwordx4
      union { int i; __half2 h; } u01, u23;
      u01.i = rec.y; u23.i = rec.z;
      float2 f01 = __half22float2(u01.h);
      float2 f23 = __half22float2(u23.h);
      const __half* rowp = x16 + ((size_t)rec.x << 6);   // SGPR row base
      float xv = __half2float(rowp[lane]);               // saddr-form gather
      d0 += f01.x; d1 += f01.y; d2 += f23.x; d3 += f23.y;
      n0 = fmaf(f01.x, xv, n0); n1 = fmaf(f01.y, xv, n1);
      n2 = fmaf(f23.x, xv, n2); n3 = fmaf(f23.y, xv, n3);
    }
  }
  float bv = bvec[lane];
  size_t ob = (size_t)node * 256 + lane;
  float o;
  o = n0 / fmaxf(d0, 1e-12f) + bv; o = (o > 0.f) ? o : (__expf(o) - 1.f); out[ob      ] = o;
  o = n1 / fmaxf(d1, 1e-12f) + bv; o = (o > 0.f) ? o : (__expf(o) - 1.f); out[ob +  64] = o;
  o = n2 / fmaxf(d2, 1e-12f) + bv; o = (o > 0.f) ? o : (__expf(o) - 1.f); out[ob + 128] = o;
  o = n3 / fmaxf(d3, 1e-12f) + bv; o = (o > 0.f) ? o : (__expf(o) - 1.f); out[ob + 192] = o;
}

// ---------------- Launch ----------------------------------------------------
extern "C" void kernel_launch(void* const* d_in, const int* in_sizes, int n_in,
                              void* d_out, int out_size, void* d_ws, size_t ws_size,
                              hipStream_t stream) {
  const float* h  = (const float*)d_in[0];
  const float* W  = (const float*)d_in[1];
  const float* Wl = (const float*)d_in[2];
  const float* Wr = (const float*)d_in[3];
  const float* b  = (const float*)d_in[4];
  const int*   ei = (const int*)d_in[5];
  float* out = (float*)d_out;   // reference output dtype is float32

  char* ws = (char*)d_ws;
  float*        x    = (float*)       (ws + 0);          // 12,800,000
  float*        el   = (float*)       (ws + 12800000);   //    800,000
  float*        er   = (float*)       (ws + 13600000);   //    800,000
  int*          bcnt = (int*)         (ws + 14400000);   // 8000*64  =    512,000
  unsigned int* raw  = (unsigned int*)(ws + 14912000);   // 8000*320*4 = 10,240,000
  int4*         recs = (int4*)        (ws + 25152000);   // 2000*1280*16 = 40,960,000
  int*          rs_s = (int*)         (ws + 66112000);   //    400,000
  int*          rs_e = (int*)         (ws + 66512000);   //    400,000
  __half*       x16  = (__half*)      (ws + 66912000);   //  6,400,000  (end ~73.3 MB)
  (void)ws_size; (void)in_sizes; (void)n_in; (void)out_size;

  hipMemsetAsync(bcnt, 0, 512000, stream);

  k_xpart  <<<GEMMB + PARTB, 256, 0, stream>>>(h, W, x, ei, bcnt, raw);
  k_eler   <<<782,   256, 0, stream>>>(x, Wl, Wr, el, er, x16);
  k_bucket <<<2000,  256, 0, stream>>>(raw, bcnt, el, er, recs, rs_s, rs_e);
  k_agg    <<<12500, 256, 0, stream>>>(x16, rs_s, rs_e, recs, b, out);
}